// Round 5
// baseline (237.436 us; speedup 1.0000x reference)
//
#include <hip/hip_runtime.h>
#include <math.h>

// ---- constants -------------------------------------------------------------
#define BATCH   32
#define LSEQ    1000
#define NHEADS  8
#define DHEAD   64
#define PE_C    (-9.210340371976184f / 512.0f)   // -ln(10000)/512

// pe[j][e]: even e -> sin(j*10000^(-e/512)), odd e -> cos with freq of e-1
__device__ __forceinline__ float pe_val(int j, int e) {
  int ef = e & ~1;
  float dv  = __expf((float)ef * PE_C);
  float arg = (float)j * dv;
  return (e & 1) ? __cosf(arg) : __sinf(arg);
}

// ---- K1: q̂[b,h] from x[b,p]; wfT4 = (Wk^T·q̂) in [e/4][bh][4] layout --------
__global__ __launch_bounds__(256) void qfold_kernel(
    const int* __restrict__ data, const int* __restrict__ lengths,
    const float* __restrict__ emb,
    const float* __restrict__ Wq, const float* __restrict__ bq,
    const float* __restrict__ Wk, const float* __restrict__ bk,
    float* __restrict__ wfT4, float* __restrict__ bias_dot) {
  int h = blockIdx.x, b = blockIdx.y;
  int p = lengths[b] - 1;
  int t = threadIdx.x;
  __shared__ float xs[512];
  __shared__ float red[256];
  __shared__ float qs[64];
  int tok = data[b * LSEQ + p];
  const float* er = emb + (size_t)tok * 512;
  xs[t]       = er[t]       + pe_val(p, t);
  xs[t + 256] = er[t + 256] + pe_val(p, t + 256);
  __syncthreads();
  // Wq matvec, 4-way K-split
  int col = h * 64 + (t & 63);
  int kp  = t >> 6;
  {
    const float* wr = Wq + (size_t)col * 512 + kp * 128;
    const float* xp = xs + kp * 128;
    float a = 0.0f;
    for (int e = 0; e < 128; e += 4) {
      float4 wv = *(const float4*)(wr + e);
      a += wv.x * xp[e] + wv.y * xp[e + 1] + wv.z * xp[e + 2] + wv.w * xp[e + 3];
    }
    red[t] = a;
  }
  __syncthreads();
  if (t < 64) {
    float qval = (red[t] + red[t + 64] + red[t + 128] + red[t + 192]
                  + bq[h * 64 + t]) * 0.125f;    // fold in 1/sqrt(64)
    qs[t] = qval;
    float bd = qval * bk[h * 64 + t];
    #pragma unroll
    for (int o = 32; o > 0; o >>= 1) bd += __shfl_xor(bd, o, 64);
    if (t == 0) bias_dot[b * NHEADS + h] = bd;
  }
  __syncthreads();
  // fold q̂ through Wk: wf[e] = sum_d qs[d] * Wk[(h*64+d)*512 + e]
  float a0 = 0.0f, a1 = 0.0f;
  const float* wkb = Wk + (size_t)(h * 64) * 512;
  for (int d = 0; d < 64; ++d) {
    float qd = qs[d];
    a0 += qd * wkb[d * 512 + t];
    a1 += qd * wkb[d * 512 + t + 256];
  }
  int bh = b * NHEADS + h;
  int e1 = t, e2 = t + 256;
  wfT4[(e1 >> 2) * 1024 + bh * 4 + (e1 & 3)] = a0;
  wfT4[(e2 >> 2) * 1024 + bh * 4 + (e2 & 3)] = a1;
}

// ---- K2: MD[r][bh] = row_r · wf[bh];  rows = emb(0..255) ++ pe(256..1255) --
__global__ __launch_bounds__(256) void foldmd_kernel(
    const float* __restrict__ emb, const float* __restrict__ wfT4,
    float* __restrict__ MD) {
  __shared__ float rows[8][512];                 // 16 KB
  int t  = threadIdx.x;
  int rr = t >> 5;                               // local row 0..7
  int e0 = (t & 31) * 16;
  int rg = blockIdx.x * 8 + rr;                  // global row 0..1255
  if (rg < 256) {
    const float* er = emb + (size_t)rg * 512 + e0;
    #pragma unroll
    for (int i = 0; i < 16; i += 4) {
      float4 v = *(const float4*)(er + i);
      rows[rr][e0 + i]     = v.x; rows[rr][e0 + i + 1] = v.y;
      rows[rr][e0 + i + 2] = v.z; rows[rr][e0 + i + 3] = v.w;
    }
  } else {
    int j = rg - 256;
    #pragma unroll
    for (int i = 0; i < 16; i += 2) {
      int e = e0 + i;
      float dv  = __expf((float)e * PE_C);
      float arg = (float)j * dv;
      rows[rr][e]     = __sinf(arg);
      rows[rr][e + 1] = __cosf(arg);
    }
  }
  __syncthreads();
  float acc[8] = {0, 0, 0, 0, 0, 0, 0, 0};
  for (int g = 0; g < 128; ++g) {                // e = 4g..4g+3
    float4 w4 = *(const float4*)(wfT4 + g * 1024 + t * 4);
    #pragma unroll
    for (int r = 0; r < 8; ++r)
      acc[r] += rows[r][4 * g] * w4.x + rows[r][4 * g + 1] * w4.y
              + rows[r][4 * g + 2] * w4.z + rows[r][4 * g + 3] * w4.w;
  }
  #pragma unroll
  for (int r = 0; r < 8; ++r)
    MD[(size_t)(blockIdx.x * 8 + r) * 256 + t] = acc[r];
}

// ---- K3: per (b,h): scores via gather -> softmax -> probs (unnorm), sums ---
__global__ __launch_bounds__(256) void attn_kernel(
    const int* __restrict__ data, const int* __restrict__ lengths,
    const float* __restrict__ MD, const float* __restrict__ bias_dot,
    float* __restrict__ probs, float* __restrict__ sums) {
  int h = blockIdx.x, b = blockIdx.y;
  int bh = b * NHEADS + h;
  int n = lengths[b];
  int t = threadIdx.x;
  __shared__ float redm[4];
  __shared__ float redsum[4];
  const float* Edot = MD;                        // [256 chars][256 bh]
  const float* Pdot = MD + 256 * 256;            // [1000 pos][256 bh]
  float bd = bias_dot[bh];
  float sreg[4];
  int   nit = 0;
  float lmax = -INFINITY;
  for (int j = t; j < n; j += 256) {
    int tok = data[b * LSEQ + j];
    float s = Edot[tok * 256 + bh] + Pdot[(size_t)j * 256 + bh] + bd;
    sreg[nit++] = s;
    lmax = fmaxf(lmax, s);
  }
  #pragma unroll
  for (int o = 32; o > 0; o >>= 1) lmax = fmaxf(lmax, __shfl_xor(lmax, o, 64));
  if ((t & 63) == 0) redm[t >> 6] = lmax;
  __syncthreads();
  float gmax = fmaxf(fmaxf(redm[0], redm[1]), fmaxf(redm[2], redm[3]));
  float ls = 0.0f;
  {
    int it = 0;
    for (int j = t; j < n; j += 256) {
      float e = __expf(sreg[it++] - gmax);
      probs[(size_t)bh * 1024 + j] = e;
      ls += e;
    }
  }
  #pragma unroll
  for (int o = 32; o > 0; o >>= 1) ls += __shfl_xor(ls, o, 64);
  if ((t & 63) == 0) redsum[t >> 6] = ls;
  __syncthreads();
  if (t == 0) sums[bh] = redsum[0] + redsum[1] + redsum[2] + redsum[3];
}

// ---- K4: y_part[b][jc][h][e] = sum_{j in chunk} p_j (emb[tok_j]+pe_j) ------
// block (jc,b); wave w owns e-slice [w*128,(w+1)*128); lane owns (sin,cos) pair
__global__ __launch_bounds__(256) void ypass_kernel(
    const int* __restrict__ data, const int* __restrict__ lengths,
    const float* __restrict__ emb, const float* __restrict__ probs,
    float* __restrict__ y_part) {
  int jc = blockIdx.x, b = blockIdx.y;
  int n = lengths[b];
  int j0 = jc * 125;
  if (j0 >= n) return;
  int cnt = min(125, n - j0);
  int t = threadIdx.x;
  __shared__ float pl[128][8];
  __shared__ int   tk[128];
  if (t < cnt) {
    tk[t] = data[b * LSEQ + j0 + t];
    #pragma unroll
    for (int h = 0; h < 8; ++h)
      pl[t][h] = probs[(size_t)(b * NHEADS + h) * 1024 + j0 + t];
  }
  __syncthreads();
  int w = t >> 6, lane = t & 63;
  int e0 = w * 128 + lane * 2;                   // even
  float dv = __expf((float)e0 * PE_C);
  float acc0[8] = {0,0,0,0,0,0,0,0};
  float acc1[8] = {0,0,0,0,0,0,0,0};
  for (int jj = 0; jj < cnt; ++jj) {
    int tok = tk[jj];
    float2 ev = *(const float2*)(emb + (size_t)tok * 512 + e0);
    float arg = (float)(j0 + jj) * dv;
    float x0 = ev.x + __sinf(arg);
    float x1 = ev.y + __cosf(arg);
    #pragma unroll
    for (int h = 0; h < 8; ++h) {
      float pj = pl[jj][h];
      acc0[h] += pj * x0;
      acc1[h] += pj * x1;
    }
  }
  size_t base = (size_t)(b * 8 + jc) * 4096 + e0;
  #pragma unroll
  for (int h = 0; h < 8; ++h) {
    float2 o; o.x = acc0[h]; o.y = acc1[h];
    *(float2*)(y_part + base + h * 512) = o;
  }
}

// ---- K5: per b: y -> ctx (Wv) -> mlp1 (W1,leaky) -> mlp2 (W2,relu,mean) ----
__global__ __launch_bounds__(256) void tail_kernel(
    const int* __restrict__ lengths, const float* __restrict__ y_part,
    const float* __restrict__ sums,
    const float* __restrict__ Wv, const float* __restrict__ bv,
    const float* __restrict__ W1, const float* __restrict__ b1,
    const float* __restrict__ W2, const float* __restrict__ b2,
    float* __restrict__ out) {
  int b = blockIdx.x;
  int t = threadIdx.x;
  __shared__ float ys[4096];                     // [h][512], 16 KB
  __shared__ float cx[512];
  __shared__ float hsd[512];
  __shared__ float invl[8];
  __shared__ float o8[8];
  int n = lengths[b];
  int nc = (n + 124) / 125;
  if (t < 8) invl[t] = 1.0f / sums[b * NHEADS + t];
  __syncthreads();
  #pragma unroll
  for (int i = 0; i < 16; ++i) {
    int idx = t + i * 256;                       // h = idx>>9, e = idx&511
    float s = 0.0f;
    for (int jc = 0; jc < nc; ++jc)
      s += y_part[(size_t)(b * 8 + jc) * 4096 + idx];
    ys[idx] = s * invl[idx >> 9];
  }
  __syncthreads();
  // ctx = Wv · y_h + bv
  #pragma unroll
  for (int cc = 0; cc < 2; ++cc) {
    int col = t + cc * 256;
    const float* wr = Wv + (size_t)col * 512;
    const float* yp = ys + ((col >> 6) << 9);
    float a = 0.0f;
    for (int e = 0; e < 512; e += 4) {
      float4 wv4 = *(const float4*)(wr + e);
      float4 yv  = *(const float4*)(yp + e);
      a += wv4.x * yv.x + wv4.y * yv.y + wv4.z * yv.z + wv4.w * yv.w;
    }
    cx[col] = a + bv[col];
  }
  __syncthreads();
  // h = leaky(W1 · ctx + b1)
  #pragma unroll
  for (int cc = 0; cc < 2; ++cc) {
    int col = t + cc * 256;
    const float* wr = W1 + (size_t)col * 512;
    float a = 0.0f;
    for (int e = 0; e < 512; e += 4) {
      float4 wv4 = *(const float4*)(wr + e);
      float4 yv  = *(const float4*)(cx + e);
      a += wv4.x * yv.x + wv4.y * yv.y + wv4.z * yv.z + wv4.w * yv.w;
    }
    a += b1[col];
    hsd[col] = (a > 0.0f) ? a : 0.01f * a;
  }
  __syncthreads();
  // out = leaky(mean(relu(W2·h + b2)))
  int j = t >> 5, sub = t & 31;
  const float* w2r = W2 + (size_t)j * 512;
  float part = 0.0f;
  for (int e = sub * 16; e < sub * 16 + 16; e += 4) {
    float4 wv4 = *(const float4*)(w2r + e);
    part += wv4.x * hsd[e] + wv4.y * hsd[e + 1]
          + wv4.z * hsd[e + 2] + wv4.w * hsd[e + 3];
  }
  #pragma unroll
  for (int o = 16; o > 0; o >>= 1) part += __shfl_xor(part, o, 64);
  if (sub == 0) o8[j] = fmaxf(part + b2[j], 0.0f);
  __syncthreads();
  if (t == 0) {
    float m = 0.0f;
    #pragma unroll
    for (int i = 0; i < 8; ++i) m += o8[i];
    m *= 0.125f;
    out[b] = (m > 0.0f) ? m : 0.01f * m;
  }
}

// ---- launcher --------------------------------------------------------------
extern "C" void kernel_launch(void* const* d_in, const int* in_sizes, int n_in,
                              void* d_out, int out_size, void* d_ws, size_t ws_size,
                              hipStream_t stream) {
  const int*   data    = (const int*)d_in[0];
  const int*   lengths = (const int*)d_in[1];
  const float* emb     = (const float*)d_in[2];
  const float* Wq      = (const float*)d_in[3];
  const float* bq      = (const float*)d_in[4];
  const float* Wk      = (const float*)d_in[5];
  const float* bk      = (const float*)d_in[6];
  const float* Wv      = (const float*)d_in[7];
  const float* bv      = (const float*)d_in[8];
  const float* W1      = (const float*)d_in[9];
  const float* b1      = (const float*)d_in[10];
  const float* W2      = (const float*)d_in[11];
  const float* b2      = (const float*)d_in[12];
  float* out = (float*)d_out;

  char* ws = (char*)d_ws;
  float* wfT4     = (float*)(ws);                //   524,288 B [e/4][256bh][4]
  float* MD       = (float*)(ws + 524288);       // 1,286,144 B [1256][256bh]
  float* bias_dot = (float*)(ws + 1810432);      //     1,024 B
  float* probs    = (float*)(ws + 1811456);      // 1,048,576 B [256bh][1024]
  float* sums     = (float*)(ws + 2860032);      //     1,024 B
  float* y_part   = (float*)(ws + 2861056);      // 4,194,304 B [b][8jc][8h][512]

  dim3 g1(NHEADS, BATCH);
  qfold_kernel<<<g1, 256, 0, stream>>>(data, lengths, emb, Wq, bq, Wk, bk,
                                       wfT4, bias_dot);
  foldmd_kernel<<<157, 256, 0, stream>>>(emb, wfT4, MD);
  dim3 g3(NHEADS, BATCH);
  attn_kernel<<<g3, 256, 0, stream>>>(data, lengths, MD, bias_dot, probs, sums);
  dim3 g4(8, BATCH);
  ypass_kernel<<<g4, 256, 0, stream>>>(data, lengths, emb, probs, y_part);
  tail_kernel<<<BATCH, 256, 0, stream>>>(lengths, y_part, sums, Wv, bv,
                                         W1, b1, W2, b2, out);
}

// Round 6
// 165.001 us; speedup vs baseline: 1.4390x; 1.4390x over previous
//
#include <hip/hip_runtime.h>
#include <math.h>

// ---- constants -------------------------------------------------------------
#define BATCH   32
#define LSEQ    1000
#define NHEADS  8
#define DHEAD   64
#define PE_C    (-9.210340371976184f / 512.0f)   // -ln(10000)/512

// pe[j][e]: even e -> sin(j*10000^(-e/512)), odd e -> cos with freq of e-1
__device__ __forceinline__ float pe_val(int j, int e) {
  int ef = e & ~1;
  float dv  = __expf((float)ef * PE_C);
  float arg = (float)j * dv;
  return (e & 1) ? __cosf(arg) : __sinf(arg);
}

// ---- K1: q̂[b,h] from x[b,p]; wfT4 = (Wk^T·q̂) in [e/4][bh][4] layout --------
__global__ __launch_bounds__(256) void qfold_kernel(
    const int* __restrict__ data, const int* __restrict__ lengths,
    const float* __restrict__ emb,
    const float* __restrict__ Wq, const float* __restrict__ bq,
    const float* __restrict__ Wk, const float* __restrict__ bk,
    float* __restrict__ wfT4, float* __restrict__ bias_dot) {
  int h = blockIdx.x, b = blockIdx.y;
  int p = lengths[b] - 1;
  int t = threadIdx.x;
  __shared__ float xs[512];
  __shared__ float red[256];
  __shared__ float qs[64];
  int tok = data[b * LSEQ + p];
  const float* er = emb + (size_t)tok * 512;
  xs[t]       = er[t]       + pe_val(p, t);
  xs[t + 256] = er[t + 256] + pe_val(p, t + 256);
  __syncthreads();
  // Wq matvec, 4-way K-split
  int col = h * 64 + (t & 63);
  int kp  = t >> 6;
  {
    const float* wr = Wq + (size_t)col * 512 + kp * 128;
    const float* xp = xs + kp * 128;
    float a = 0.0f;
    for (int e = 0; e < 128; e += 4) {
      float4 wv = *(const float4*)(wr + e);
      a += wv.x * xp[e] + wv.y * xp[e + 1] + wv.z * xp[e + 2] + wv.w * xp[e + 3];
    }
    red[t] = a;
  }
  __syncthreads();
  if (t < 64) {
    float qval = (red[t] + red[t + 64] + red[t + 128] + red[t + 192]
                  + bq[h * 64 + t]) * 0.125f;    // fold in 1/sqrt(64)
    qs[t] = qval;
    float bd = qval * bk[h * 64 + t];
    #pragma unroll
    for (int o = 32; o > 0; o >>= 1) bd += __shfl_xor(bd, o, 64);
    if (t == 0) bias_dot[b * NHEADS + h] = bd;
  }
  __syncthreads();
  // fold q̂ through Wk: wf[e] = sum_d qs[d] * Wk[(h*64+d)*512 + e]
  float a0 = 0.0f, a1 = 0.0f;
  const float* wkb = Wk + (size_t)(h * 64) * 512;
  for (int d = 0; d < 64; ++d) {
    float qd = qs[d];
    a0 += qd * wkb[d * 512 + t];
    a1 += qd * wkb[d * 512 + t + 256];
  }
  int bh = b * NHEADS + h;
  int e1 = t, e2 = t + 256;
  wfT4[(e1 >> 2) * 1024 + bh * 4 + (e1 & 3)] = a0;
  wfT4[(e2 >> 2) * 1024 + bh * 4 + (e2 & 3)] = a1;
}

// ---- K2: MD[r][bh] = row_r · wf[bh];  rows = emb(0..255) ++ pe(256..1255) --
__global__ __launch_bounds__(256) void foldmd_kernel(
    const float* __restrict__ emb, const float* __restrict__ wfT4,
    float* __restrict__ MD) {
  __shared__ float rows[8][512];                 // 16 KB
  int t  = threadIdx.x;
  int rr = t >> 5;                               // local row 0..7
  int e0 = (t & 31) * 16;
  int rg = blockIdx.x * 8 + rr;                  // global row 0..1255
  if (rg < 256) {
    const float* er = emb + (size_t)rg * 512 + e0;
    #pragma unroll
    for (int i = 0; i < 16; i += 4) {
      float4 v = *(const float4*)(er + i);
      rows[rr][e0 + i]     = v.x; rows[rr][e0 + i + 1] = v.y;
      rows[rr][e0 + i + 2] = v.z; rows[rr][e0 + i + 3] = v.w;
    }
  } else {
    int j = rg - 256;
    #pragma unroll
    for (int i = 0; i < 16; i += 2) {
      int e = e0 + i;
      float dv  = __expf((float)e * PE_C);
      float arg = (float)j * dv;
      rows[rr][e]     = __sinf(arg);
      rows[rr][e + 1] = __cosf(arg);
    }
  }
  __syncthreads();
  float acc[8] = {0, 0, 0, 0, 0, 0, 0, 0};
  for (int g = 0; g < 128; ++g) {                // e = 4g..4g+3
    float4 w4 = *(const float4*)(wfT4 + g * 1024 + t * 4);
    #pragma unroll
    for (int r = 0; r < 8; ++r)
      acc[r] += rows[r][4 * g] * w4.x + rows[r][4 * g + 1] * w4.y
              + rows[r][4 * g + 2] * w4.z + rows[r][4 * g + 3] * w4.w;
  }
  #pragma unroll
  for (int r = 0; r < 8; ++r)
    MD[(size_t)(blockIdx.x * 8 + r) * 256 + t] = acc[r];
}

// ---- K3: per (b,h): scores via gather -> softmax -> probs (unnorm), sums ---
__global__ __launch_bounds__(256) void attn_kernel(
    const int* __restrict__ data, const int* __restrict__ lengths,
    const float* __restrict__ MD, const float* __restrict__ bias_dot,
    float* __restrict__ probs, float* __restrict__ sums) {
  int h = blockIdx.x, b = blockIdx.y;
  int bh = b * NHEADS + h;
  int n = lengths[b];
  int t = threadIdx.x;
  __shared__ float redm[4];
  __shared__ float redsum[4];
  const float* Edot = MD;                        // [256 chars][256 bh]
  const float* Pdot = MD + 256 * 256;            // [1000 pos][256 bh]
  float bd = bias_dot[bh];
  float sreg[4];
  int   nit = 0;
  float lmax = -INFINITY;
  for (int j = t; j < n; j += 256) {
    int tok = data[b * LSEQ + j];
    float s = Edot[tok * 256 + bh] + Pdot[(size_t)j * 256 + bh] + bd;
    sreg[nit++] = s;
    lmax = fmaxf(lmax, s);
  }
  #pragma unroll
  for (int o = 32; o > 0; o >>= 1) lmax = fmaxf(lmax, __shfl_xor(lmax, o, 64));
  if ((t & 63) == 0) redm[t >> 6] = lmax;
  __syncthreads();
  float gmax = fmaxf(fmaxf(redm[0], redm[1]), fmaxf(redm[2], redm[3]));
  float ls = 0.0f;
  {
    int it = 0;
    for (int j = t; j < n; j += 256) {
      float e = __expf(sreg[it++] - gmax);
      probs[(size_t)bh * 1024 + j] = e;
      ls += e;
    }
  }
  #pragma unroll
  for (int o = 32; o > 0; o >>= 1) ls += __shfl_xor(ls, o, 64);
  if ((t & 63) == 0) redsum[t >> 6] = ls;
  __syncthreads();
  if (t == 0) sums[bh] = redsum[0] + redsum[1] + redsum[2] + redsum[3];
}

// ---- K4: y_part[b][jc][h][e] = sum_{j in chunk} p_j (emb[tok_j]+pe_j) ------
// block (jc,b); wave w owns e-slice [w*128,(w+1)*128); lane owns (sin,cos) pair
__global__ __launch_bounds__(256) void ypass_kernel(
    const int* __restrict__ data, const int* __restrict__ lengths,
    const float* __restrict__ emb, const float* __restrict__ probs,
    float* __restrict__ y_part) {
  int jc = blockIdx.x, b = blockIdx.y;
  int n = lengths[b];
  int j0 = jc * 125;
  if (j0 >= n) return;
  int cnt = min(125, n - j0);
  int t = threadIdx.x;
  __shared__ float pl[128][8];
  __shared__ int   tk[128];
  if (t < cnt) {
    tk[t] = data[b * LSEQ + j0 + t];
    #pragma unroll
    for (int h = 0; h < 8; ++h)
      pl[t][h] = probs[(size_t)(b * NHEADS + h) * 1024 + j0 + t];
  }
  __syncthreads();
  int w = t >> 6, lane = t & 63;
  int e0 = w * 128 + lane * 2;                   // even
  float dv = __expf((float)e0 * PE_C);
  float acc0[8] = {0,0,0,0,0,0,0,0};
  float acc1[8] = {0,0,0,0,0,0,0,0};
  for (int jj = 0; jj < cnt; ++jj) {
    int tok = tk[jj];
    float2 ev = *(const float2*)(emb + (size_t)tok * 512 + e0);
    float arg = (float)(j0 + jj) * dv;
    float x0 = ev.x + __sinf(arg);
    float x1 = ev.y + __cosf(arg);
    #pragma unroll
    for (int h = 0; h < 8; ++h) {
      float pj = pl[jj][h];
      acc0[h] += pj * x0;
      acc1[h] += pj * x1;
    }
  }
  size_t base = (size_t)(b * 8 + jc) * 4096 + e0;
  #pragma unroll
  for (int h = 0; h < 8; ++h) {
    float2 o; o.x = acc0[h]; o.y = acc1[h];
    *(float2*)(y_part + base + h * 512) = o;
  }
}

// ---- K5: ctx[b, h*64+d] = Wv[h*64+d,:]·(y_h/S) + bv  (grid 8 x 32) ---------
__global__ __launch_bounds__(256) void ctx_kernel(
    const int* __restrict__ lengths, const float* __restrict__ y_part,
    const float* __restrict__ sums, const float* __restrict__ Wv,
    const float* __restrict__ bv, float* __restrict__ ctx) {
  int h = blockIdx.x, b = blockIdx.y;
  int t = threadIdx.x;
  __shared__ float ys[512];
  __shared__ float red[256];
  int n = lengths[b];
  int nc = (n + 124) / 125;
  float inv = 1.0f / sums[b * NHEADS + h];
  float s0 = 0.0f, s1 = 0.0f;
  for (int jc = 0; jc < nc; ++jc) {
    size_t base = (size_t)(b * 8 + jc) * 4096 + h * 512;
    s0 += y_part[base + t];
    s1 += y_part[base + t + 256];
  }
  ys[t]       = s0 * inv;
  ys[t + 256] = s1 * inv;
  __syncthreads();
  int col = h * 64 + (t & 63);
  int kp  = t >> 6;                              // 4-way K split
  const float* wr = Wv + (size_t)col * 512 + kp * 128;
  const float* xp = ys + kp * 128;
  float a = 0.0f;
  for (int e = 0; e < 128; e += 4) {
    float4 wv4 = *(const float4*)(wr + e);
    a += wv4.x * xp[e] + wv4.y * xp[e + 1] + wv4.z * xp[e + 2] + wv4.w * xp[e + 3];
  }
  red[t] = a;
  __syncthreads();
  if (t < 64)
    ctx[b * 512 + h * 64 + t] =
        red[t] + red[t + 64] + red[t + 128] + red[t + 192] + bv[h * 64 + t];
}

// ---- K6: MLP layer 1 (leaky_relu), grid 8 x 32 -----------------------------
__global__ __launch_bounds__(256) void mlp1_kernel(
    const float* __restrict__ ctx, const float* __restrict__ W1,
    const float* __restrict__ b1, float* __restrict__ hs) {
  int chunk = blockIdx.x, b = blockIdx.y;
  int t = threadIdx.x;
  __shared__ float xs[512];
  __shared__ float red[256];
  xs[t]       = ctx[b * 512 + t];
  xs[t + 256] = ctx[b * 512 + t + 256];
  __syncthreads();
  int col = chunk * 64 + (t & 63);
  int kp  = t >> 6;
  const float* wr = W1 + (size_t)col * 512 + kp * 128;
  const float* xp = xs + kp * 128;
  float a = 0.0f;
  for (int e = 0; e < 128; e += 4) {
    float4 wv = *(const float4*)(wr + e);
    a += wv.x * xp[e] + wv.y * xp[e + 1] + wv.z * xp[e + 2] + wv.w * xp[e + 3];
  }
  red[t] = a;
  __syncthreads();
  if (t < 64) {
    float v = red[t] + red[t + 64] + red[t + 128] + red[t + 192] + b1[chunk * 64 + t];
    hs[b * 512 + chunk * 64 + t] = (v > 0.0f) ? v : 0.01f * v;
  }
}

// ---- K7: MLP layer 2 + mean + leaky ----------------------------------------
__global__ __launch_bounds__(256) void mlp2_kernel(
    const float* __restrict__ hs, const float* __restrict__ W2,
    const float* __restrict__ b2, float* __restrict__ out) {
  int b = blockIdx.x, t = threadIdx.x;
  __shared__ float o8[8];
  int j = t >> 5, sub = t & 31;
  const float* hr  = hs + (size_t)b * 512;
  const float* w2r = W2 + (size_t)j * 512;
  float part = 0.0f;
  for (int e = sub * 16; e < sub * 16 + 16; e += 4) {
    float4 wv = *(const float4*)(w2r + e);
    float4 hv = *(const float4*)(hr + e);
    part += wv.x * hv.x + wv.y * hv.y + wv.z * hv.z + wv.w * hv.w;
  }
  #pragma unroll
  for (int o = 16; o > 0; o >>= 1) part += __shfl_xor(part, o, 64);
  if (sub == 0) o8[j] = fmaxf(part + b2[j], 0.0f);   // relu
  __syncthreads();
  if (t == 0) {
    float m = 0.0f;
    #pragma unroll
    for (int i = 0; i < 8; ++i) m += o8[i];
    m *= 0.125f;
    out[b] = (m > 0.0f) ? m : 0.01f * m;
  }
}

// ---- launcher --------------------------------------------------------------
extern "C" void kernel_launch(void* const* d_in, const int* in_sizes, int n_in,
                              void* d_out, int out_size, void* d_ws, size_t ws_size,
                              hipStream_t stream) {
  const int*   data    = (const int*)d_in[0];
  const int*   lengths = (const int*)d_in[1];
  const float* emb     = (const float*)d_in[2];
  const float* Wq      = (const float*)d_in[3];
  const float* bq      = (const float*)d_in[4];
  const float* Wk      = (const float*)d_in[5];
  const float* bk      = (const float*)d_in[6];
  const float* Wv      = (const float*)d_in[7];
  const float* bv      = (const float*)d_in[8];
  const float* W1      = (const float*)d_in[9];
  const float* b1      = (const float*)d_in[10];
  const float* W2      = (const float*)d_in[11];
  const float* b2      = (const float*)d_in[12];
  float* out = (float*)d_out;

  char* ws = (char*)d_ws;
  float* wfT4     = (float*)(ws);                //   524,288 B [e/4][256bh][4]
  float* MD       = (float*)(ws + 524288);       // 1,286,144 B [1256][256bh]
  float* bias_dot = (float*)(ws + 1810432);      //     1,024 B
  float* probs    = (float*)(ws + 1811456);      // 1,048,576 B [256bh][1024]
  float* sums     = (float*)(ws + 2860032);      //     1,024 B
  float* y_part   = (float*)(ws + 2861056);      // 4,194,304 B [b][8jc][8h][512]
  float* ctx      = (float*)(ws + 7055360);      //    65,536 B
  float* hs       = (float*)(ws + 7120896);      //    65,536 B

  dim3 g1(NHEADS, BATCH);
  qfold_kernel<<<g1, 256, 0, stream>>>(data, lengths, emb, Wq, bq, Wk, bk,
                                       wfT4, bias_dot);
  foldmd_kernel<<<157, 256, 0, stream>>>(emb, wfT4, MD);
  dim3 g3(NHEADS, BATCH);
  attn_kernel<<<g3, 256, 0, stream>>>(data, lengths, MD, bias_dot, probs, sums);
  dim3 g4(8, BATCH);
  ypass_kernel<<<g4, 256, 0, stream>>>(data, lengths, emb, probs, y_part);
  dim3 g5(NHEADS, BATCH);
  ctx_kernel<<<g5, 256, 0, stream>>>(lengths, y_part, sums, Wv, bv, ctx);
  dim3 g6(8, BATCH);
  mlp1_kernel<<<g6, 256, 0, stream>>>(ctx, W1, b1, hs);
  mlp2_kernel<<<BATCH, 256, 0, stream>>>(hs, W2, b2, out);
}

// Round 7
// 148.617 us; speedup vs baseline: 1.5976x; 1.1102x over previous
//
#include <hip/hip_runtime.h>
#include <math.h>

// ---- constants -------------------------------------------------------------
#define BATCH   32
#define LSEQ    1000
#define NHEADS  8
#define DHEAD   64
#define PE_C    (-9.210340371976184f / 512.0f)   // -ln(10000)/512

// pe[j][e]: even e -> sin(j*10000^(-e/512)), odd e -> cos with freq of e-1
__device__ __forceinline__ float pe_val(int j, int e) {
  int ef = e & ~1;
  float dv  = __expf((float)ef * PE_C);
  float arg = (float)j * dv;
  return (e & 1) ? __cosf(arg) : __sinf(arg);
}

// ---- K1: q̂[b,h] from x[b,p]; wfT4 = (Wk^T·q̂) in [e/4][bh][4] layout --------
__global__ __launch_bounds__(256) void qfold_kernel(
    const int* __restrict__ data, const int* __restrict__ lengths,
    const float* __restrict__ emb,
    const float* __restrict__ Wq, const float* __restrict__ bq,
    const float* __restrict__ Wk, const float* __restrict__ bk,
    float* __restrict__ wfT4, float* __restrict__ bias_dot) {
  int h = blockIdx.x, b = blockIdx.y;
  int p = lengths[b] - 1;
  int t = threadIdx.x;
  __shared__ float xs[512];
  __shared__ float red[256];
  __shared__ float qs[64];
  int tok = data[b * LSEQ + p];
  const float* er = emb + (size_t)tok * 512;
  xs[t]       = er[t]       + pe_val(p, t);
  xs[t + 256] = er[t + 256] + pe_val(p, t + 256);
  __syncthreads();
  // Wq matvec, 4-way K-split
  int col = h * 64 + (t & 63);
  int kp  = t >> 6;
  {
    const float* wr = Wq + (size_t)col * 512 + kp * 128;
    const float* xp = xs + kp * 128;
    float a = 0.0f;
    for (int e = 0; e < 128; e += 4) {
      float4 wv = *(const float4*)(wr + e);
      a += wv.x * xp[e] + wv.y * xp[e + 1] + wv.z * xp[e + 2] + wv.w * xp[e + 3];
    }
    red[t] = a;
  }
  __syncthreads();
  if (t < 64) {
    float qval = (red[t] + red[t + 64] + red[t + 128] + red[t + 192]
                  + bq[h * 64 + t]) * 0.125f;    // fold in 1/sqrt(64)
    qs[t] = qval;
    float bd = qval * bk[h * 64 + t];
    #pragma unroll
    for (int o = 32; o > 0; o >>= 1) bd += __shfl_xor(bd, o, 64);
    if (t == 0) bias_dot[b * NHEADS + h] = bd;
  }
  __syncthreads();
  // fold q̂ through Wk: wf[e] = sum_d qs[d] * Wk[(h*64+d)*512 + e]
  float a0 = 0.0f, a1 = 0.0f;
  const float* wkb = Wk + (size_t)(h * 64) * 512;
  for (int d = 0; d < 64; ++d) {
    float qd = qs[d];
    a0 += qd * wkb[d * 512 + t];
    a1 += qd * wkb[d * 512 + t + 256];
  }
  int bh = b * NHEADS + h;
  int e1 = t, e2 = t + 256;
  wfT4[(e1 >> 2) * 1024 + bh * 4 + (e1 & 3)] = a0;
  wfT4[(e2 >> 2) * 1024 + bh * 4 + (e2 & 3)] = a1;
}

// ---- K2: MD[r][bh] = row_r · wf[bh];  rows = emb(0..255) ++ pe(256..1255) --
// 2 rows x 256 cols per block, grid 628 -> ~10 waves/CU.
__global__ __launch_bounds__(256) void foldmd_kernel(
    const float* __restrict__ emb, const float* __restrict__ wfT4,
    float* __restrict__ MD) {
  __shared__ float rows[2][512];                 // 4 KB
  int t  = threadIdx.x;
  int rr = t >> 7;                               // local row 0..1
  int e0 = (t & 127) * 4;                        // 4 consecutive elems
  int rg = blockIdx.x * 2 + rr;                  // global row 0..1255
  if (rg < 256) {
    float4 v = *(const float4*)(emb + (size_t)rg * 512 + e0);
    *(float4*)(&rows[rr][e0]) = v;
  } else {
    int j = rg - 256;
    float4 v;
    float dv0 = __expf((float)e0 * PE_C);
    float dv1 = __expf((float)(e0 + 2) * PE_C);
    float a0 = (float)j * dv0, a1 = (float)j * dv1;
    v.x = __sinf(a0); v.y = __cosf(a0);
    v.z = __sinf(a1); v.w = __cosf(a1);
    *(float4*)(&rows[rr][e0]) = v;
  }
  __syncthreads();
  float acc0 = 0.0f, acc1 = 0.0f;
  #pragma unroll 8
  for (int g = 0; g < 128; ++g) {                // e = 4g..4g+3
    float4 w4 = *(const float4*)(wfT4 + g * 1024 + t * 4);
    float4 r0 = *(const float4*)(&rows[0][4 * g]);
    float4 r1 = *(const float4*)(&rows[1][4 * g]);
    acc0 += r0.x * w4.x + r0.y * w4.y + r0.z * w4.z + r0.w * w4.w;
    acc1 += r1.x * w4.x + r1.y * w4.y + r1.z * w4.z + r1.w * w4.w;
  }
  MD[(size_t)(blockIdx.x * 2)     * 256 + t] = acc0;
  MD[(size_t)(blockIdx.x * 2 + 1) * 256 + t] = acc1;
}

// ---- K3: per (b,h): scores via gather -> softmax -> probs (unnorm), sums ---
__global__ __launch_bounds__(256) void attn_kernel(
    const int* __restrict__ data, const int* __restrict__ lengths,
    const float* __restrict__ MD, const float* __restrict__ bias_dot,
    float* __restrict__ probs, float* __restrict__ sums) {
  int h = blockIdx.x, b = blockIdx.y;
  int bh = b * NHEADS + h;
  int n = lengths[b];
  int t = threadIdx.x;
  __shared__ float redm[4];
  __shared__ float redsum[4];
  const float* Edot = MD;                        // [256 chars][256 bh]
  const float* Pdot = MD + 256 * 256;            // [1000 pos][256 bh]
  float bd = bias_dot[bh];
  float sreg[4];
  int   nit = 0;
  float lmax = -INFINITY;
  for (int j = t; j < n; j += 256) {
    int tok = data[b * LSEQ + j];
    float s = Edot[tok * 256 + bh] + Pdot[(size_t)j * 256 + bh] + bd;
    sreg[nit++] = s;
    lmax = fmaxf(lmax, s);
  }
  #pragma unroll
  for (int o = 32; o > 0; o >>= 1) lmax = fmaxf(lmax, __shfl_xor(lmax, o, 64));
  if ((t & 63) == 0) redm[t >> 6] = lmax;
  __syncthreads();
  float gmax = fmaxf(fmaxf(redm[0], redm[1]), fmaxf(redm[2], redm[3]));
  float ls = 0.0f;
  {
    int it = 0;
    for (int j = t; j < n; j += 256) {
      float e = __expf(sreg[it++] - gmax);
      probs[(size_t)bh * 1024 + j] = e;
      ls += e;
    }
  }
  #pragma unroll
  for (int o = 32; o > 0; o >>= 1) ls += __shfl_xor(ls, o, 64);
  if ((t & 63) == 0) redsum[t >> 6] = ls;
  __syncthreads();
  if (t == 0) sums[bh] = redsum[0] + redsum[1] + redsum[2] + redsum[3];
}

// ---- K4: y_part[b][jc][h][e] = sum_{j in chunk} p_j (emb[tok_j]+pe_j) ------
// block (jc,b); wave w owns e-slice [w*128,(w+1)*128); lane owns (sin,cos) pair
__global__ __launch_bounds__(256) void ypass_kernel(
    const int* __restrict__ data, const int* __restrict__ lengths,
    const float* __restrict__ emb, const float* __restrict__ probs,
    float* __restrict__ y_part) {
  int jc = blockIdx.x, b = blockIdx.y;
  int n = lengths[b];
  int j0 = jc * 125;
  if (j0 >= n) return;
  int cnt = min(125, n - j0);
  int t = threadIdx.x;
  __shared__ float pl[128][8];
  __shared__ int   tk[128];
  if (t < cnt) {
    tk[t] = data[b * LSEQ + j0 + t];
    #pragma unroll
    for (int h = 0; h < 8; ++h)
      pl[t][h] = probs[(size_t)(b * NHEADS + h) * 1024 + j0 + t];
  }
  __syncthreads();
  int w = t >> 6, lane = t & 63;
  int e0 = w * 128 + lane * 2;                   // even
  float dv = __expf((float)e0 * PE_C);
  float acc0[8] = {0,0,0,0,0,0,0,0};
  float acc1[8] = {0,0,0,0,0,0,0,0};
  for (int jj = 0; jj < cnt; ++jj) {
    int tok = tk[jj];
    float2 ev = *(const float2*)(emb + (size_t)tok * 512 + e0);
    float arg = (float)(j0 + jj) * dv;
    float x0 = ev.x + __sinf(arg);
    float x1 = ev.y + __cosf(arg);
    #pragma unroll
    for (int h = 0; h < 8; ++h) {
      float pj = pl[jj][h];
      acc0[h] += pj * x0;
      acc1[h] += pj * x1;
    }
  }
  size_t base = (size_t)(b * 8 + jc) * 4096 + e0;
  #pragma unroll
  for (int h = 0; h < 8; ++h) {
    float2 o; o.x = acc0[h]; o.y = acc1[h];
    *(float2*)(y_part + base + h * 512) = o;
  }
}

// ---- K5: ctx[b, h*64+d] = Wv[h*64+d,:]·(y_h/S) + bv  (grid 8 x 32) ---------
__global__ __launch_bounds__(256) void ctx_kernel(
    const int* __restrict__ lengths, const float* __restrict__ y_part,
    const float* __restrict__ sums, const float* __restrict__ Wv,
    const float* __restrict__ bv, float* __restrict__ ctx) {
  int h = blockIdx.x, b = blockIdx.y;
  int t = threadIdx.x;
  __shared__ float ys[512];
  __shared__ float red[256];
  int n = lengths[b];
  int nc = (n + 124) / 125;
  float inv = 1.0f / sums[b * NHEADS + h];
  float s0 = 0.0f, s1 = 0.0f;
  for (int jc = 0; jc < nc; ++jc) {
    size_t base = (size_t)(b * 8 + jc) * 4096 + h * 512;
    s0 += y_part[base + t];
    s1 += y_part[base + t + 256];
  }
  ys[t]       = s0 * inv;
  ys[t + 256] = s1 * inv;
  __syncthreads();
  int col = h * 64 + (t & 63);
  int kp  = t >> 6;                              // 4-way K split
  const float* wr = Wv + (size_t)col * 512 + kp * 128;
  const float* xp = ys + kp * 128;
  float a = 0.0f;
  for (int e = 0; e < 128; e += 4) {
    float4 wv4 = *(const float4*)(wr + e);
    a += wv4.x * xp[e] + wv4.y * xp[e + 1] + wv4.z * xp[e + 2] + wv4.w * xp[e + 3];
  }
  red[t] = a;
  __syncthreads();
  if (t < 64)
    ctx[b * 512 + h * 64 + t] =
        red[t] + red[t + 64] + red[t + 128] + red[t + 192] + bv[h * 64 + t];
}

// ---- K6: MLP layer 1 (leaky_relu), grid 8 x 32 -----------------------------
__global__ __launch_bounds__(256) void mlp1_kernel(
    const float* __restrict__ ctx, const float* __restrict__ W1,
    const float* __restrict__ b1, float* __restrict__ hs) {
  int chunk = blockIdx.x, b = blockIdx.y;
  int t = threadIdx.x;
  __shared__ float xs[512];
  __shared__ float red[256];
  xs[t]       = ctx[b * 512 + t];
  xs[t + 256] = ctx[b * 512 + t + 256];
  __syncthreads();
  int col = chunk * 64 + (t & 63);
  int kp  = t >> 6;
  const float* wr = W1 + (size_t)col * 512 + kp * 128;
  const float* xp = xs + kp * 128;
  float a = 0.0f;
  for (int e = 0; e < 128; e += 4) {
    float4 wv = *(const float4*)(wr + e);
    a += wv.x * xp[e] + wv.y * xp[e + 1] + wv.z * xp[e + 2] + wv.w * xp[e + 3];
  }
  red[t] = a;
  __syncthreads();
  if (t < 64) {
    float v = red[t] + red[t + 64] + red[t + 128] + red[t + 192] + b1[chunk * 64 + t];
    hs[b * 512 + chunk * 64 + t] = (v > 0.0f) ? v : 0.01f * v;
  }
}

// ---- K7: MLP layer 2 + mean + leaky ----------------------------------------
__global__ __launch_bounds__(256) void mlp2_kernel(
    const float* __restrict__ hs, const float* __restrict__ W2,
    const float* __restrict__ b2, float* __restrict__ out) {
  int b = blockIdx.x, t = threadIdx.x;
  __shared__ float o8[8];
  int j = t >> 5, sub = t & 31;
  const float* hr  = hs + (size_t)b * 512;
  const float* w2r = W2 + (size_t)j * 512;
  float part = 0.0f;
  for (int e = sub * 16; e < sub * 16 + 16; e += 4) {
    float4 wv = *(const float4*)(w2r + e);
    float4 hv = *(const float4*)(hr + e);
    part += wv.x * hv.x + wv.y * hv.y + wv.z * hv.z + wv.w * hv.w;
  }
  #pragma unroll
  for (int o = 16; o > 0; o >>= 1) part += __shfl_xor(part, o, 64);
  if (sub == 0) o8[j] = fmaxf(part + b2[j], 0.0f);   // relu
  __syncthreads();
  if (t == 0) {
    float m = 0.0f;
    #pragma unroll
    for (int i = 0; i < 8; ++i) m += o8[i];
    m *= 0.125f;
    out[b] = (m > 0.0f) ? m : 0.01f * m;
  }
}

// ---- launcher --------------------------------------------------------------
extern "C" void kernel_launch(void* const* d_in, const int* in_sizes, int n_in,
                              void* d_out, int out_size, void* d_ws, size_t ws_size,
                              hipStream_t stream) {
  const int*   data    = (const int*)d_in[0];
  const int*   lengths = (const int*)d_in[1];
  const float* emb     = (const float*)d_in[2];
  const float* Wq      = (const float*)d_in[3];
  const float* bq      = (const float*)d_in[4];
  const float* Wk      = (const float*)d_in[5];
  const float* bk      = (const float*)d_in[6];
  const float* Wv      = (const float*)d_in[7];
  const float* bv      = (const float*)d_in[8];
  const float* W1      = (const float*)d_in[9];
  const float* b1      = (const float*)d_in[10];
  const float* W2      = (const float*)d_in[11];
  const float* b2      = (const float*)d_in[12];
  float* out = (float*)d_out;

  char* ws = (char*)d_ws;
  float* wfT4     = (float*)(ws);                //   524,288 B [e/4][256bh][4]
  float* MD       = (float*)(ws + 524288);       // 1,286,144 B [1256][256bh]
  float* bias_dot = (float*)(ws + 1810432);      //     1,024 B
  float* probs    = (float*)(ws + 1811456);      // 1,048,576 B [256bh][1024]
  float* sums     = (float*)(ws + 2860032);      //     1,024 B
  float* y_part   = (float*)(ws + 2861056);      // 4,194,304 B [b][8jc][8h][512]
  float* ctx      = (float*)(ws + 7055360);      //    65,536 B
  float* hs       = (float*)(ws + 7120896);      //    65,536 B

  dim3 g1(NHEADS, BATCH);
  qfold_kernel<<<g1, 256, 0, stream>>>(data, lengths, emb, Wq, bq, Wk, bk,
                                       wfT4, bias_dot);
  foldmd_kernel<<<628, 256, 0, stream>>>(emb, wfT4, MD);
  dim3 g3(NHEADS, BATCH);
  attn_kernel<<<g3, 256, 0, stream>>>(data, lengths, MD, bias_dot, probs, sums);
  dim3 g4(8, BATCH);
  ypass_kernel<<<g4, 256, 0, stream>>>(data, lengths, emb, probs, y_part);
  dim3 g5(NHEADS, BATCH);
  ctx_kernel<<<g5, 256, 0, stream>>>(lengths, y_part, sums, Wv, bv, ctx);
  dim3 g6(8, BATCH);
  mlp1_kernel<<<g6, 256, 0, stream>>>(ctx, W1, b1, hs);
  mlp2_kernel<<<BATCH, 256, 0, stream>>>(hs, W2, b2, out);
}

// Round 8
// 140.658 us; speedup vs baseline: 1.6880x; 1.0566x over previous
//
#include <hip/hip_runtime.h>
#include <math.h>

// ---- constants -------------------------------------------------------------
#define BATCH   32
#define LSEQ    1000
#define NHEADS  8
#define DHEAD   64
#define PE_C    (-9.210340371976184f / 512.0f)   // -ln(10000)/512

// pe[j][e]: even e -> sin(j*10000^(-e/512)), odd e -> cos with freq of e-1
__device__ __forceinline__ float pe_val(int j, int e) {
  int ef = e & ~1;
  float dv  = __expf((float)ef * PE_C);
  float arg = (float)j * dv;
  return (e & 1) ? __cosf(arg) : __sinf(arg);
}

// ---- K1: q̂[b,h] from x[b,p]; wfT4 = (Wk^T·q̂) in [e/4][bh][4] layout --------
__global__ __launch_bounds__(256) void qfold_kernel(
    const int* __restrict__ data, const int* __restrict__ lengths,
    const float* __restrict__ emb,
    const float* __restrict__ Wq, const float* __restrict__ bq,
    const float* __restrict__ Wk, const float* __restrict__ bk,
    float* __restrict__ wfT4, float* __restrict__ bias_dot) {
  int h = blockIdx.x, b = blockIdx.y;
  int p = lengths[b] - 1;
  int t = threadIdx.x;
  __shared__ float xs[512];
  __shared__ float red[256];
  __shared__ float qs[64];
  int tok = data[b * LSEQ + p];
  const float* er = emb + (size_t)tok * 512;
  xs[t]       = er[t]       + pe_val(p, t);
  xs[t + 256] = er[t + 256] + pe_val(p, t + 256);
  __syncthreads();
  // Wq matvec, 4-way K-split
  int col = h * 64 + (t & 63);
  int kp  = t >> 6;
  {
    const float* wr = Wq + (size_t)col * 512 + kp * 128;
    const float* xp = xs + kp * 128;
    float a = 0.0f;
    for (int e = 0; e < 128; e += 4) {
      float4 wv = *(const float4*)(wr + e);
      a += wv.x * xp[e] + wv.y * xp[e + 1] + wv.z * xp[e + 2] + wv.w * xp[e + 3];
    }
    red[t] = a;
  }
  __syncthreads();
  if (t < 64) {
    float qval = (red[t] + red[t + 64] + red[t + 128] + red[t + 192]
                  + bq[h * 64 + t]) * 0.125f;    // fold in 1/sqrt(64)
    qs[t] = qval;
    float bd = qval * bk[h * 64 + t];
    #pragma unroll
    for (int o = 32; o > 0; o >>= 1) bd += __shfl_xor(bd, o, 64);
    if (t == 0) bias_dot[b * NHEADS + h] = bd;
  }
  __syncthreads();
  // fold q̂ through Wk: wf[e] = sum_d qs[d] * Wk[(h*64+d)*512 + e]
  float a0 = 0.0f, a1 = 0.0f;
  const float* wkb = Wk + (size_t)(h * 64) * 512;
  for (int d = 0; d < 64; ++d) {
    float qd = qs[d];
    a0 += qd * wkb[d * 512 + t];
    a1 += qd * wkb[d * 512 + t + 256];
  }
  int bh = b * NHEADS + h;
  int e1 = t, e2 = t + 256;
  wfT4[(e1 >> 2) * 1024 + bh * 4 + (e1 & 3)] = a0;
  wfT4[(e2 >> 2) * 1024 + bh * 4 + (e2 & 3)] = a1;
}

// ---- K2: MD[r][bh] = row_r · wf[bh] (+bias_dot for emb rows) ---------------
// rows = emb(0..255) ++ pe(256..1255). Block: 8 rows x 64 bh; grid (157,4).
__global__ __launch_bounds__(256) void foldmd_kernel(
    const float* __restrict__ emb, const float* __restrict__ wfT4,
    const float* __restrict__ bias_dot, float* __restrict__ MD) {
  __shared__ float rows[8 * 512];                // 16 KB
  int t   = threadIdx.x;
  int r0  = blockIdx.x * 8;
  int bh0 = blockIdx.y * 64;
  // stage 8 rows, coalesced float4
  #pragma unroll
  for (int i = 0; i < 4; ++i) {
    int fi = t + i * 256;                        // float4 index 0..1023
    int rr = fi >> 7;                            // local row
    int e  = (fi & 127) * 4;
    int rg = r0 + rr;
    float4 v;
    if (rg < 256) {
      v = *(const float4*)(emb + (size_t)rg * 512 + e);
    } else {
      int j = rg - 256;
      float dv0 = __expf((float)e * PE_C);
      float dv1 = __expf((float)(e + 2) * PE_C);
      float a0 = (float)j * dv0, a1 = (float)j * dv1;
      v.x = __sinf(a0); v.y = __cosf(a0);
      v.z = __sinf(a1); v.w = __cosf(a1);
    }
    *(float4*)(&rows[rr * 512 + e]) = v;
  }
  __syncthreads();
  int bh_l = t & 63;
  int rp   = t >> 6;                             // wave -> row pair
  const float* rw0 = rows + (2 * rp) * 512;
  const float* rw1 = rows + (2 * rp + 1) * 512;
  const float* wp  = wfT4 + (bh0 + bh_l) * 4;
  float a0 = 0.0f, a1 = 0.0f;
  #pragma unroll 8
  for (int g = 0; g < 128; ++g) {
    float4 w4 = *(const float4*)(wp + g * 1024);
    float4 v0 = *(const float4*)(rw0 + 4 * g);   // wave-uniform -> broadcast
    float4 v1 = *(const float4*)(rw1 + 4 * g);
    a0 += v0.x * w4.x + v0.y * w4.y + v0.z * w4.z + v0.w * w4.w;
    a1 += v1.x * w4.x + v1.y * w4.y + v1.z * w4.z + v1.w * w4.w;
  }
  float bd = (r0 < 256) ? bias_dot[bh0 + bh_l] : 0.0f;
  MD[(size_t)(r0 + 2 * rp)     * 256 + bh0 + bh_l] = a0 + bd;
  MD[(size_t)(r0 + 2 * rp + 1) * 256 + bh0 + bh_l] = a1 + bd;
}

// ---- K3: fused scores + chunk softmax + weighted emb/pe sum per (b,jc) -----
// chunk = 125 keys. Outputs: mS[b][jc][h] = (m, S), y_part[b][jc][h][512].
__global__ __launch_bounds__(256) void attn_ypass_kernel(
    const int* __restrict__ data, const int* __restrict__ lengths,
    const float* __restrict__ emb, const float* __restrict__ MD,
    float* __restrict__ mS, float* __restrict__ y_part) {
  int jc = blockIdx.x, b = blockIdx.y;
  int n = lengths[b];
  int j0 = jc * 125;
  if (j0 >= n) return;
  int cnt = min(125, n - j0);
  int t = threadIdx.x;
  __shared__ float sl[125][8];                   // scores -> probs
  __shared__ int   tk[125];
  __shared__ float redw[4][8];
  __shared__ float m_sh[8], s_sh[8];
  const float* Edot = MD;                        // [256 tok][256 bh] (+bias)
  const float* Pdot = MD + 256 * 256;            // [1000 pos][256 bh]
  // phase 1: scores (thread j, 8 heads each)
  if (t < 125) {
    if (t < cnt) {
      int tok = data[b * LSEQ + j0 + t];
      tk[t] = tok;
      const float* er = Edot + (size_t)tok * 256 + b * 8;
      const float* pr = Pdot + (size_t)(j0 + t) * 256 + b * 8;
      float4 e0 = *(const float4*)(er);
      float4 e1 = *(const float4*)(er + 4);
      float4 p0 = *(const float4*)(pr);
      float4 p1 = *(const float4*)(pr + 4);
      sl[t][0] = e0.x + p0.x; sl[t][1] = e0.y + p0.y;
      sl[t][2] = e0.z + p0.z; sl[t][3] = e0.w + p0.w;
      sl[t][4] = e1.x + p1.x; sl[t][5] = e1.y + p1.y;
      sl[t][6] = e1.z + p1.z; sl[t][7] = e1.w + p1.w;
    } else {
      #pragma unroll
      for (int h = 0; h < 8; ++h) sl[t][h] = -INFINITY;
    }
  }
  __syncthreads();
  // phase 2: per-h max over j. thread: h = t&7, jg = t>>3 (0..31)
  int h = t & 7, jg = t >> 3, w = t >> 6;
  {
    float m = -INFINITY;
    for (int j = jg; j < 125; j += 32) m = fmaxf(m, sl[j][h]);
    #pragma unroll
    for (int o = 8; o < 64; o <<= 1) m = fmaxf(m, __shfl_xor(m, o, 64));
    if ((t & 63) < 8) redw[w][t & 7] = m;
  }
  __syncthreads();
  if (t < 8)
    m_sh[t] = fmaxf(fmaxf(redw[0][t], redw[1][t]),
                    fmaxf(redw[2][t], redw[3][t]));
  __syncthreads();
  // phase 3: probs + per-h sum
  {
    float mh = m_sh[h];
    float sum = 0.0f;
    for (int j = jg; j < 125; j += 32) {
      float p = __expf(sl[j][h] - mh);           // exp(-inf)=0 for invalid j
      sl[j][h] = p;
      sum += p;
    }
    #pragma unroll
    for (int o = 8; o < 64; o <<= 1) sum += __shfl_xor(sum, o, 64);
    if ((t & 63) < 8) redw[w][t & 7] = sum;
  }
  __syncthreads();
  if (t < 8)
    s_sh[t] = redw[0][t] + redw[1][t] + redw[2][t] + redw[3][t];
  __syncthreads();
  // phase 4: y accumulation; wave owns e-slice, lane owns (sin,cos) pair
  int lane = t & 63;
  int e0i = w * 128 + lane * 2;
  float dv = __expf((float)e0i * PE_C);
  float acc0[8] = {0,0,0,0,0,0,0,0};
  float acc1[8] = {0,0,0,0,0,0,0,0};
  for (int jj = 0; jj < cnt; ++jj) {
    int tok = tk[jj];
    float2 ev = *(const float2*)(emb + (size_t)tok * 512 + e0i);
    float arg = (float)(j0 + jj) * dv;
    float x0 = ev.x + __sinf(arg);
    float x1 = ev.y + __cosf(arg);
    #pragma unroll
    for (int hh = 0; hh < 8; ++hh) {
      float pj = sl[jj][hh];                     // broadcast
      acc0[hh] += pj * x0;
      acc1[hh] += pj * x1;
    }
  }
  size_t base = (size_t)(b * 8 + jc) * 4096 + e0i;
  #pragma unroll
  for (int hh = 0; hh < 8; ++hh) {
    float2 o; o.x = acc0[hh]; o.y = acc1[hh];
    *(float2*)(y_part + base + hh * 512) = o;
  }
  if (t < 8) {
    float2 ms; ms.x = m_sh[t]; ms.y = s_sh[t];
    *(float2*)(mS + ((size_t)(b * 8 + jc) * 8 + t) * 2) = ms;
  }
}

// ---- K4: ctx[b, h*64+d] = Wv[h*64+d,:]·(combine(y)/S) + bv  (grid 8x32) ----
__global__ __launch_bounds__(256) void ctx_kernel(
    const int* __restrict__ lengths, const float* __restrict__ y_part,
    const float* __restrict__ mS, const float* __restrict__ Wv,
    const float* __restrict__ bv, float* __restrict__ ctx) {
  int h = blockIdx.x, b = blockIdx.y;
  int t = threadIdx.x;
  __shared__ float ys[512];
  __shared__ float red[256];
  int n = lengths[b];
  int nc = (n + 124) / 125;
  float M = -INFINITY;
  for (int jc = 0; jc < nc; ++jc)
    M = fmaxf(M, mS[((size_t)(b * 8 + jc) * 8 + h) * 2]);
  float S = 0.0f, s0 = 0.0f, s1 = 0.0f;
  for (int jc = 0; jc < nc; ++jc) {
    float2 ms = *(const float2*)(mS + ((size_t)(b * 8 + jc) * 8 + h) * 2);
    float wgt = __expf(ms.x - M);
    S += wgt * ms.y;
    size_t base = (size_t)(b * 8 + jc) * 4096 + h * 512;
    s0 += wgt * y_part[base + t];
    s1 += wgt * y_part[base + t + 256];
  }
  float inv = 1.0f / S;
  ys[t]       = s0 * inv;
  ys[t + 256] = s1 * inv;
  __syncthreads();
  int col = h * 64 + (t & 63);
  int kp  = t >> 6;                              // 4-way K split
  const float* wr = Wv + (size_t)col * 512 + kp * 128;
  const float* xp = ys + kp * 128;
  float a = 0.0f;
  for (int e = 0; e < 128; e += 4) {
    float4 wv4 = *(const float4*)(wr + e);
    a += wv4.x * xp[e] + wv4.y * xp[e + 1] + wv4.z * xp[e + 2] + wv4.w * xp[e + 3];
  }
  red[t] = a;
  __syncthreads();
  if (t < 64)
    ctx[b * 512 + h * 64 + t] =
        red[t] + red[t + 64] + red[t + 128] + red[t + 192] + bv[h * 64 + t];
}

// ---- K5: MLP layer 1 (leaky_relu), grid 8 x 32 -----------------------------
__global__ __launch_bounds__(256) void mlp1_kernel(
    const float* __restrict__ ctx, const float* __restrict__ W1,
    const float* __restrict__ b1, float* __restrict__ hs) {
  int chunk = blockIdx.x, b = blockIdx.y;
  int t = threadIdx.x;
  __shared__ float xs[512];
  __shared__ float red[256];
  xs[t]       = ctx[b * 512 + t];
  xs[t + 256] = ctx[b * 512 + t + 256];
  __syncthreads();
  int col = chunk * 64 + (t & 63);
  int kp  = t >> 6;
  const float* wr = W1 + (size_t)col * 512 + kp * 128;
  const float* xp = xs + kp * 128;
  float a = 0.0f;
  for (int e = 0; e < 128; e += 4) {
    float4 wv = *(const float4*)(wr + e);
    a += wv.x * xp[e] + wv.y * xp[e + 1] + wv.z * xp[e + 2] + wv.w * xp[e + 3];
  }
  red[t] = a;
  __syncthreads();
  if (t < 64) {
    float v = red[t] + red[t + 64] + red[t + 128] + red[t + 192] + b1[chunk * 64 + t];
    hs[b * 512 + chunk * 64 + t] = (v > 0.0f) ? v : 0.01f * v;
  }
}

// ---- K6: MLP layer 2 + mean + leaky ----------------------------------------
__global__ __launch_bounds__(256) void mlp2_kernel(
    const float* __restrict__ hs, const float* __restrict__ W2,
    const float* __restrict__ b2, float* __restrict__ out) {
  int b = blockIdx.x, t = threadIdx.x;
  __shared__ float o8[8];
  int j = t >> 5, sub = t & 31;
  const float* hr  = hs + (size_t)b * 512;
  const float* w2r = W2 + (size_t)j * 512;
  float part = 0.0f;
  for (int e = sub * 16; e < sub * 16 + 16; e += 4) {
    float4 wv = *(const float4*)(w2r + e);
    float4 hv = *(const float4*)(hr + e);
    part += wv.x * hv.x + wv.y * hv.y + wv.z * hv.z + wv.w * hv.w;
  }
  #pragma unroll
  for (int o = 16; o > 0; o >>= 1) part += __shfl_xor(part, o, 64);
  if (sub == 0) o8[j] = fmaxf(part + b2[j], 0.0f);   // relu
  __syncthreads();
  if (t == 0) {
    float m = 0.0f;
    #pragma unroll
    for (int i = 0; i < 8; ++i) m += o8[i];
    m *= 0.125f;
    out[b] = (m > 0.0f) ? m : 0.01f * m;
  }
}

// ---- launcher --------------------------------------------------------------
extern "C" void kernel_launch(void* const* d_in, const int* in_sizes, int n_in,
                              void* d_out, int out_size, void* d_ws, size_t ws_size,
                              hipStream_t stream) {
  const int*   data    = (const int*)d_in[0];
  const int*   lengths = (const int*)d_in[1];
  const float* emb     = (const float*)d_in[2];
  const float* Wq      = (const float*)d_in[3];
  const float* bq      = (const float*)d_in[4];
  const float* Wk      = (const float*)d_in[5];
  const float* bk      = (const float*)d_in[6];
  const float* Wv      = (const float*)d_in[7];
  const float* bv      = (const float*)d_in[8];
  const float* W1      = (const float*)d_in[9];
  const float* b1      = (const float*)d_in[10];
  const float* W2      = (const float*)d_in[11];
  const float* b2      = (const float*)d_in[12];
  float* out = (float*)d_out;

  char* ws = (char*)d_ws;
  float* wfT4     = (float*)(ws);                //   524,288 B [e/4][256bh][4]
  float* MD       = (float*)(ws + 524288);       // 1,286,144 B [1256][256bh]
  float* bias_dot = (float*)(ws + 1810432);      //     1,024 B
  float* mS       = (float*)(ws + 1811456);      //    16,384 B [b][jc][h](m,S)
  float* y_part   = (float*)(ws + 1827840);      // 4,194,304 B [b][8jc][8h][512]
  float* ctx      = (float*)(ws + 6022144);      //    65,536 B
  float* hs       = (float*)(ws + 6087680);      //    65,536 B

  dim3 g1(NHEADS, BATCH);
  qfold_kernel<<<g1, 256, 0, stream>>>(data, lengths, emb, Wq, bq, Wk, bk,
                                       wfT4, bias_dot);
  dim3 g2(157, 4);
  foldmd_kernel<<<g2, 256, 0, stream>>>(emb, wfT4, bias_dot, MD);
  dim3 g3(8, BATCH);
  attn_ypass_kernel<<<g3, 256, 0, stream>>>(data, lengths, emb, MD, mS, y_part);
  dim3 g4(NHEADS, BATCH);
  ctx_kernel<<<g4, 256, 0, stream>>>(lengths, y_part, mS, Wv, bv, ctx);
  dim3 g5(8, BATCH);
  mlp1_kernel<<<g5, 256, 0, stream>>>(ctx, W1, b1, hs);
  mlp2_kernel<<<BATCH, 256, 0, stream>>>(hs, W2, b2, out);
}